// Round 9
// baseline (68.858 us; speedup 1.0000x reference)
//
#include <hip/hip_runtime.h>
#include <hip/hip_bf16.h>

// out = conv9(in @ M^T),  M = Wout @ Win   (conv commutes with the channel GEMMs)
// g(d) = N(0,1) pdf, taps |d|<=4.
// R9: fused_gc A-path direct global->frag (no A LDS round trip), depth-2 named
//     reg prefetch, one vmcnt(8)+barrier per step; gemm_m B-transpose via b64.

typedef unsigned short u16;
typedef unsigned int u32;
typedef unsigned long long u64;
typedef __attribute__((ext_vector_type(8))) short bf16x8;
typedef __attribute__((ext_vector_type(8))) unsigned short u16x8;
typedef __attribute__((ext_vector_type(4))) unsigned short u16x4;
typedef __attribute__((ext_vector_type(4))) float f32x4;
typedef __attribute__((ext_vector_type(2))) u32 u32x2;

typedef __attribute__((address_space(1))) const void* as1_cvp;
typedef __attribute__((address_space(3))) void* as3_vp;

#define EDIM 512
#define NROW 16384
#define ROWS_OUT 120
#define MBLK 137                 // ceil(16384/120)
#define NWG (MBLK * 4)           // 548
#define YSTR 136

__device__ __forceinline__ float b2f(u16 x) {
  union { u32 u; float f; } c; c.u = ((u32)x) << 16; return c.f;
}
__device__ __forceinline__ u16 f2b(float x) {
  union { float f; u32 u; } c; c.f = x;
  return (u16)((c.u + 0x7fffu + ((c.u >> 16) & 1u)) >> 16);  // RNE
}
__device__ __forceinline__ u32 cvtpk(float lo, float hi) {
  u32 r;
  asm("v_cvt_pk_bf16_f32 %0, %1, %2" : "=v"(r) : "v"(lo), "v"(hi));
  return r;
}
__device__ __forceinline__ void async_cp16(const void* g, void* l) {
  __builtin_amdgcn_global_load_lds((as1_cvp)(u64)g, (as3_vp)(u32)(u64)l, 16, 0, 0);
}
union bfu { u32 w[4]; bf16x8 v; };

// ---------------------------------------------------------------------------
// Kernel 1: M[f,e] = sum_c Wout[f,c]*Win[c,e] (512^3). 64x64 tiles, BK=128,
// 4 steps, raw barriers + lgkm-only waits. B-transpose: 4c x 8e register
// repack -> 8 aligned ds_write_b64 (replaces 32 scalar b16 scatters).
// ---------------------------------------------------------------------------
__global__ __launch_bounds__(256) void gemm_m(const float* __restrict__ Wout,
                                              const float* __restrict__ Win,
                                              u16* __restrict__ Mm) {
  __shared__ u16 la[64 * 136];   // A [f][c]
  __shared__ u16 lbt[64 * 136];  // B^T [e][c]
  int t = threadIdx.x;
  int w = t >> 6, l = t & 63, lr = l & 15, lk = l >> 4;
  int f0 = (int)(blockIdx.x >> 3) * 64, e0 = (int)(blockIdx.x & 7) * 64;
  int arow = t >> 2, acol = (t & 3) * 32;  // A: 64 rows x 128 k
  int cq = t >> 3, eo = (t & 7) * 8;       // B: c-quad 4*cq, e-octet eo
  const float* pA = Wout + (u64)(f0 + arow) * EDIM + acol;
  const float* pB = Win + (u64)(4 * cq) * EDIM + e0 + eo;
  f32x4 a8[8], b8[8];  // b8[r*2+h] = Win[4cq+r][eo + h*4 ..]
#pragma unroll
  for (int i = 0; i < 8; ++i) a8[i] = *(const f32x4*)(pA + i * 4);
#pragma unroll
  for (int r = 0; r < 4; ++r) {
    b8[r * 2 + 0] = *(const f32x4*)(pB + r * EDIM);
    b8[r * 2 + 1] = *(const f32x4*)(pB + r * EDIM + 4);
  }
  f32x4 acc[4] = {};
  for (int kt = 0; kt < 4; ++kt) {
#pragma unroll
    for (int i = 0; i < 4; ++i) {  // A regs -> bf16 LDS [f][c]
      u16x8 o;
#pragma unroll
      for (int q = 0; q < 4; ++q) { o[q] = f2b(a8[2 * i][q]); o[4 + q] = f2b(a8[2 * i + 1][q]); }
      *(u16x8*)(la + arow * 136 + acol + i * 8) = o;
    }
#pragma unroll
    for (int j = 0; j < 8; ++j) {  // B^T: pack c-quad for e = eo+j -> b64
      u32x2 p;
      p[0] = cvtpk(b8[0 + (j >> 2)][j & 3], b8[2 + (j >> 2)][j & 3]);
      p[1] = cvtpk(b8[4 + (j >> 2)][j & 3], b8[6 + (j >> 2)][j & 3]);
      *(u32x2*)(lbt + (eo + j) * 136 + 4 * cq) = p;
    }
    asm volatile("s_waitcnt lgkmcnt(0)" ::: "memory");
    __builtin_amdgcn_sched_barrier(0);
    __builtin_amdgcn_s_barrier();
    if (kt < 3) {
      pA += 128; pB += (u64)128 * EDIM;
#pragma unroll
      for (int i = 0; i < 8; ++i) a8[i] = *(const f32x4*)(pA + i * 4);
#pragma unroll
      for (int r = 0; r < 4; ++r) {
        b8[r * 2 + 0] = *(const f32x4*)(pB + r * EDIM);
        b8[r * 2 + 1] = *(const f32x4*)(pB + r * EDIM + 4);
      }
    }
#pragma unroll
    for (int kk = 0; kk < 128; kk += 32) {
      bf16x8 a = *(const bf16x8*)(la + (w * 16 + lr) * 136 + kk + lk * 8);
#pragma unroll
      for (int ni = 0; ni < 4; ++ni) {
        bf16x8 bb = *(const bf16x8*)(lbt + (ni * 16 + lr) * 136 + kk + lk * 8);
        acc[ni] = __builtin_amdgcn_mfma_f32_16x16x32_bf16(a, bb, acc[ni], 0, 0, 0);
      }
    }
    asm volatile("s_waitcnt lgkmcnt(0)" ::: "memory");
    __builtin_amdgcn_sched_barrier(0);
    __builtin_amdgcn_s_barrier();
  }
#pragma unroll
  for (int ni = 0; ni < 4; ++ni)
#pragma unroll
    for (int r = 0; r < 4; ++r)
      Mm[(u64)(f0 + w * 16 + lk * 4 + r) * EDIM + e0 + ni * 16 + lr] = f2b(acc[ni][r]);
}

// ---------------------------------------------------------------------------
// 9-tap conv from Y[128][136] bf16 LDS -> fp32 out (circular window).
// ---------------------------------------------------------------------------
template <bool EDGE>
__device__ __forceinline__ void conv_store(const u16* __restrict__ Y, int t,
                                           int m0c, int n0, float* __restrict__ out) {
  const float G[5] = {0.39894228040143270f, 0.24197072451914337f,
                      0.053990966513188063f, 0.0044318484119380075f,
                      1.3383022576488537e-4f};
  int qc = t & 31, grp = t >> 5;
  int rl0 = 4 + grp * 15;
  const u16* Yb = Y + qc * 4;
  f32x4 wnd[9];
#pragma unroll
  for (int i = 0; i < 9; ++i) {
    u16x4 yv = *(const u16x4*)(Yb + (rl0 - 4 + i) * YSTR);
#pragma unroll
    for (int q = 0; q < 4; ++q) wnd[i][q] = b2f(yv[q]);
  }
#pragma unroll
  for (int j = 0; j < 15; ++j) {
    int rg = m0c + rl0 + j;
    f32x4 a = {};
#pragma unroll
    for (int k = 0; k < 9; ++k) {
      float g = G[k < 4 ? 4 - k : k - 4];
      if (EDGE) {
        int rt = rg + k - 4;
        g = ((rt >> 12) == (rg >> 12)) ? g : 0.0f;
      }
#pragma unroll
      for (int q = 0; q < 4; ++q) a[q] += g * wnd[(j + k) % 9][q];
    }
    if (!EDGE || rg < NROW)
      *(f32x4*)(out + (u64)rg * EDIM + n0 + qc * 4) = a;
    if (j < 14) {
      u16x4 yv = *(const u16x4*)(Yb + (rl0 + j + 5) * YSTR);
#pragma unroll
      for (int q = 0; q < 4; ++q) wnd[j % 9][q] = b2f(yv[q]);
    }
  }
}

// ---------------------------------------------------------------------------
// Kernel 2: fused GEMM + conv. 128x128 tile, BK=32, 16 steps.
// A: global -> frag registers directly (no LDS), depth-2 prefetch (P/Q sets).
// B: double-buffered global_load_lds (pre-swizzled source + swizzled read).
// Per step: cvt(A) | B-async | A-loads(kt+2) | ds_read B + 16 MFMA | vmcnt(N) | bar.
// Invariant entering step kt: outstanding VMEM = A8(kt+1) only; step-end
// vmcnt(8) retires {A8(kt), B2(kt)} leaving A8(kt+1) in flight.
// ---------------------------------------------------------------------------
#define KSTEP(KT, S0, S1, BCUR, BNXT, VM)                                      \
  {                                                                            \
    bf16x8 af[4];                                                              \
    _Pragma("unroll") for (int mi = 0; mi < 4; ++mi) {                         \
      bfu u_;                                                                  \
      u_.w[0] = cvtpk(S0[mi][0], S0[mi][1]);                                   \
      u_.w[1] = cvtpk(S0[mi][2], S0[mi][3]);                                   \
      u_.w[2] = cvtpk(S1[mi][0], S1[mi][1]);                                   \
      u_.w[3] = cvtpk(S1[mi][2], S1[mi][3]);                                   \
      af[mi] = u_.v;                                                           \
    }                                                                          \
    __builtin_amdgcn_sched_barrier(0);                                         \
    async_cp16(bsrc0 + ((KT) + 1) * 32, lds + (BNXT) + t * 8);                 \
    async_cp16(bsrc1 + ((KT) + 1) * 32, lds + (BNXT) + 2048 + t * 8);          \
    __builtin_amdgcn_sched_barrier(0);                                         \
    if ((KT) + 2 < 16) {                                                       \
      _Pragma("unroll") for (int mi = 0; mi < 4; ++mi) {                       \
        S0[mi] = *(const f32x4*)(in + rowA[mi] + ((KT) + 2) * 32);             \
        S1[mi] = *(const f32x4*)(in + rowA[mi] + ((KT) + 2) * 32 + 4);         \
      }                                                                        \
    }                                                                          \
    __builtin_amdgcn_sched_barrier(0);                                         \
    bf16x8 bv[4];                                                              \
    _Pragma("unroll") for (int ni = 0; ni < 4; ++ni)                           \
        bv[ni] = *(const bf16x8*)(lds + (BCUR) + brd[ni]);                     \
    _Pragma("unroll") for (int mi = 0; mi < 4; ++mi)                           \
      _Pragma("unroll") for (int ni = 0; ni < 4; ++ni)                         \
          acc[mi][ni] = __builtin_amdgcn_mfma_f32_16x16x32_bf16(               \
              af[mi], bv[ni], acc[mi][ni], 0, 0, 0);                           \
    asm volatile("s_waitcnt vmcnt(" #VM ")" ::: "memory");                     \
    __builtin_amdgcn_sched_barrier(0);                                         \
    __builtin_amdgcn_s_barrier();                                              \
  }

__global__ __launch_bounds__(256, 2) void fused_gc(const float* __restrict__ in,
                                                   const u16* __restrict__ Mm,
                                                   float* __restrict__ out) {
  __shared__ u16 lds[17408];  // 34.8KB: B0 @0 (4096 u16) | B1 @4096 | Y overlays all
  int t = threadIdx.x;
  int l = t & 63, lr = l & 15, lk = l >> 4;
  int wv = t >> 6, wr = wv >> 1, wc = wv & 1;

  // bijective XCD swizzle (m204)
  int b = (int)blockIdx.x;
  int q = NWG >> 3, r = NWG & 7;  // 68, 4
  int xcd = b & 7, off = b >> 3;
  int wg = (xcd < r ? xcd * (q + 1) : r * (q + 1) + (xcd - r) * q) + off;
  int ib = wg >> 2;
  int n0 = (wg & 3) << 7;
  int m0c = ib * ROWS_OUT - 4;  // first computed row (halo 4)

  // A fragment row offsets (clamped), element units: lane lr -> row, lk -> k-octet
  u32 rowA[4];
#pragma unroll
  for (int mi = 0; mi < 4; ++mi) {
    int rg = m0c + wr * 64 + mi * 16 + lr;
    rg = rg < 0 ? 0 : (rg > NROW - 1 ? NROW - 1 : rg);
    rowA[mi] = (u32)rg * EDIM + lk * 8;
  }
  // B source (pre-swizzled octets): swz(row) = (row ^ row>>2) & 3
  int brow0 = t >> 2, slot = t & 3;
  int brow1 = brow0 + 64;
  const u16* bsrc0 = Mm + (u64)(n0 + brow0) * EDIM + ((slot ^ ((brow0 ^ (brow0 >> 2)) & 3)) * 8);
  const u16* bsrc1 = Mm + (u64)(n0 + brow1) * EDIM + ((slot ^ ((brow1 ^ (brow1 >> 2)) & 3)) * 8);
  int brd[4];
#pragma unroll
  for (int ni = 0; ni < 4; ++ni) {
    int row = wc * 64 + ni * 16 + lr;
    brd[ni] = (row * 32 + lk * 8) ^ (((row ^ (row >> 2)) & 3) << 3);
  }

  f32x4 acc[4][4] = {};
  f32x4 aP0[4], aP1[4], aQ0[4], aQ1[4];

  // ---- prologue: A(0)->P, A(1)->Q, B(0)->buf0, full drain, barrier
#pragma unroll
  for (int mi = 0; mi < 4; ++mi) {
    aP0[mi] = *(const f32x4*)(in + rowA[mi]);
    aP1[mi] = *(const f32x4*)(in + rowA[mi] + 4);
  }
#pragma unroll
  for (int mi = 0; mi < 4; ++mi) {
    aQ0[mi] = *(const f32x4*)(in + rowA[mi] + 32);
    aQ1[mi] = *(const f32x4*)(in + rowA[mi] + 36);
  }
  async_cp16(bsrc0, lds + t * 8);
  async_cp16(bsrc1, lds + 2048 + t * 8);
  asm volatile("s_waitcnt vmcnt(0)" ::: "memory");
  __builtin_amdgcn_sched_barrier(0);
  __builtin_amdgcn_s_barrier();

  // ---- steps 0..13 (P/Q pairs), peel 14 (vmcnt 0), 15 (no issues)
  for (int kt = 0; kt < 14; kt += 2) {
    KSTEP(kt,     aP0, aP1, 0,    4096, 8)
    KSTEP(kt + 1, aQ0, aQ1, 4096, 0,    8)
  }
  KSTEP(14, aP0, aP1, 0, 4096, 0)
  {  // step 15: cvt Q + MFMA from buf1, no prefetch
    bf16x8 af[4];
#pragma unroll
    for (int mi = 0; mi < 4; ++mi) {
      bfu u_;
      u_.w[0] = cvtpk(aQ0[mi][0], aQ0[mi][1]);
      u_.w[1] = cvtpk(aQ0[mi][2], aQ0[mi][3]);
      u_.w[2] = cvtpk(aQ1[mi][0], aQ1[mi][1]);
      u_.w[3] = cvtpk(aQ1[mi][2], aQ1[mi][3]);
      af[mi] = u_.v;
    }
    bf16x8 bv[4];
#pragma unroll
    for (int ni = 0; ni < 4; ++ni) bv[ni] = *(const bf16x8*)(lds + 4096 + brd[ni]);
#pragma unroll
    for (int mi = 0; mi < 4; ++mi)
#pragma unroll
      for (int ni = 0; ni < 4; ++ni)
        acc[mi][ni] = __builtin_amdgcn_mfma_f32_16x16x32_bf16(af[mi], bv[ni],
                                                              acc[mi][ni], 0, 0, 0);
  }
  __syncthreads();  // all B reads done before Y overlays the buffers

  // ---- epilogue: acc -> Y[128][136] bf16, 9-tap conv, fp32 out
  u16* Y = lds;
#pragma unroll
  for (int mi = 0; mi < 4; ++mi)
#pragma unroll
    for (int ni = 0; ni < 4; ++ni)
#pragma unroll
      for (int rr = 0; rr < 4; ++rr)
        Y[(wr * 64 + mi * 16 + lk * 4 + rr) * YSTR + wc * 64 + ni * 16 + lr] =
            f2b(acc[mi][ni][rr]);
  __syncthreads();

  bool edge = ((m0c >> 12) != ((m0c + 127) >> 12));
  if (edge)
    conv_store<true>(Y, t, m0c, n0, out);
  else
    conv_store<false>(Y, t, m0c, n0, out);
}

extern "C" void kernel_launch(void* const* d_in, const int* in_sizes, int n_in,
                              void* d_out, int out_size, void* d_ws, size_t ws_size,
                              hipStream_t stream) {
  const float* in   = (const float*)d_in[0];
  const float* Win  = (const float*)d_in[1];
  const float* Wout = (const float*)d_in[2];
  float* outp = (float*)d_out;

  u16* Mm = (u16*)d_ws;

  hipLaunchKernelGGL(gemm_m,   dim3(64), dim3(256), 0, stream, Wout, Win, Mm);
  hipLaunchKernelGGL(fused_gc, dim3(NWG), dim3(256), 0, stream, in, Mm, outp);
}

// Round 10
// 39.891 us; speedup vs baseline: 1.7262x; 1.7262x over previous
//
#include <hip/hip_runtime.h>
#include <hip/hip_bf16.h>

// out = conv9(in) @ M^T,  M = Wout @ Win   (conv commutes with the channel GEMMs)
// R10: de-fused for counter visibility.
//   prep:    blocks 0..63 gemm_m (M -> ws, bf16); blocks 64.. conv9 (U -> ws, bf16)
//   gemm_out: pure bf16 GEMM  out[16384,512] = U @ M^T, fp32 out.

typedef unsigned short u16;
typedef unsigned int u32;
typedef unsigned long long u64;
typedef __attribute__((ext_vector_type(8))) short bf16x8;
typedef __attribute__((ext_vector_type(8))) unsigned short u16x8;
typedef __attribute__((ext_vector_type(4))) float f32x4;
typedef __attribute__((ext_vector_type(2))) u32 u32x2;

typedef __attribute__((address_space(1))) const void* as1_cvp;
typedef __attribute__((address_space(3))) void* as3_vp;

#define EDIM 512
#define NROW 16384
#define NCONVB 4096              // conv blocks: 16384 rows * 64 thr/row / 256
#define GOUT 512                 // gemm_out blocks: 128 m * 4 n

__device__ __forceinline__ float b2f(u16 x) {
  union { u32 u; float f; } c; c.u = ((u32)x) << 16; return c.f;
}
__device__ __forceinline__ u16 f2b(float x) {
  union { float f; u32 u; } c; c.f = x;
  return (u16)((c.u + 0x7fffu + ((c.u >> 16) & 1u)) >> 16);  // RNE
}
__device__ __forceinline__ u32 cvtpk(float lo, float hi) {
  u32 r;
  asm("v_cvt_pk_bf16_f32 %0, %1, %2" : "=v"(r) : "v"(lo), "v"(hi));
  return r;
}
__device__ __forceinline__ void async_cp16(const void* g, void* l) {
  __builtin_amdgcn_global_load_lds((as1_cvp)(u64)g, (as3_vp)(u32)(u64)l, 16, 0, 0);
}

// ---------------------------------------------------------------------------
// prep: [blocks 0..63]   M[f,e] = sum_c Wout[f,c]*Win[c,e], bf16 -> Mm
//       [blocks 64..]    U[r,e] = sum_{|d|<=4} g(d)*in[r+d,e], bf16 -> Uo
// ---------------------------------------------------------------------------
__global__ __launch_bounds__(256) void prep(const float* __restrict__ in,
                                            const float* __restrict__ Win,
                                            const float* __restrict__ Wout,
                                            u16* __restrict__ Mm,
                                            u16* __restrict__ Uo) {
  __shared__ u16 plds[17408];  // gemm_m: la | lbt (8704 u16 each)
  int bid = (int)blockIdx.x, t = threadIdx.x;
  if (bid < 64) {
    // ---- gemm_m: 64x64 tile, BK=128, 4 steps, raw barriers, lgkm-only waits
    u16* la = plds;          // A [f][c], stride 136
    u16* lbt = plds + 8704;  // B^T [e][c], stride 136
    int w = t >> 6, l = t & 63, lr = l & 15, lk = l >> 4;
    int f0 = (bid >> 3) * 64, e0 = (bid & 7) * 64;
    int arow = t >> 2, acol = (t & 3) * 32;  // A: 64 rows x 128 k
    int cq = t >> 3, eo = (t & 7) * 8;       // B: c-quad 4*cq, e-octet eo
    const float* pA = Wout + (u64)(f0 + arow) * EDIM + acol;
    const float* pB = Win + (u64)(4 * cq) * EDIM + e0 + eo;
    f32x4 a8[8], b8[8];
#pragma unroll
    for (int i = 0; i < 8; ++i) a8[i] = *(const f32x4*)(pA + i * 4);
#pragma unroll
    for (int r = 0; r < 4; ++r) {
      b8[r * 2 + 0] = *(const f32x4*)(pB + r * EDIM);
      b8[r * 2 + 1] = *(const f32x4*)(pB + r * EDIM + 4);
    }
    f32x4 acc[4] = {};
    for (int kt = 0; kt < 4; ++kt) {
#pragma unroll
      for (int i = 0; i < 4; ++i) {
        u16x8 o;
#pragma unroll
        for (int q = 0; q < 4; ++q) { o[q] = f2b(a8[2 * i][q]); o[4 + q] = f2b(a8[2 * i + 1][q]); }
        *(u16x8*)(la + arow * 136 + acol + i * 8) = o;
      }
#pragma unroll
      for (int j = 0; j < 8; ++j) {
        u32x2 p;
        p[0] = cvtpk(b8[0 + (j >> 2)][j & 3], b8[2 + (j >> 2)][j & 3]);
        p[1] = cvtpk(b8[4 + (j >> 2)][j & 3], b8[6 + (j >> 2)][j & 3]);
        *(u32x2*)(lbt + (eo + j) * 136 + 4 * cq) = p;
      }
      asm volatile("s_waitcnt lgkmcnt(0)" ::: "memory");
      __builtin_amdgcn_sched_barrier(0);
      __builtin_amdgcn_s_barrier();
      if (kt < 3) {
        pA += 128; pB += (u64)128 * EDIM;
#pragma unroll
        for (int i = 0; i < 8; ++i) a8[i] = *(const f32x4*)(pA + i * 4);
#pragma unroll
        for (int r = 0; r < 4; ++r) {
          b8[r * 2 + 0] = *(const f32x4*)(pB + r * EDIM);
          b8[r * 2 + 1] = *(const f32x4*)(pB + r * EDIM + 4);
        }
      }
#pragma unroll
      for (int kk = 0; kk < 128; kk += 32) {
        bf16x8 a = *(const bf16x8*)(la + (w * 16 + lr) * 136 + kk + lk * 8);
#pragma unroll
        for (int ni = 0; ni < 4; ++ni) {
          bf16x8 bb = *(const bf16x8*)(lbt + (ni * 16 + lr) * 136 + kk + lk * 8);
          acc[ni] = __builtin_amdgcn_mfma_f32_16x16x32_bf16(a, bb, acc[ni], 0, 0, 0);
        }
      }
      asm volatile("s_waitcnt lgkmcnt(0)" ::: "memory");
      __builtin_amdgcn_sched_barrier(0);
      __builtin_amdgcn_s_barrier();
    }
#pragma unroll
    for (int ni = 0; ni < 4; ++ni)
#pragma unroll
      for (int r = 0; r < 4; ++r)
        Mm[(u64)(f0 + w * 16 + lk * 4 + r) * EDIM + e0 + ni * 16 + lr] = f2b(acc[ni][r]);
  } else {
    // ---- conv: one wave = one row (64 thr x 8 cols); taps are wave-uniform
    const float G[5] = {0.39894228040143270f, 0.24197072451914337f,
                        0.053990966513188063f, 0.0044318484119380075f,
                        1.3383022576488537e-4f};
    int gid = (bid - 64) * 256 + t;
    int r = gid >> 6, c = (gid & 63) * 8;
    int s = r & 4095;
    const float* base = in + (u64)r * EDIM + c;
    float a[8] = {0.f, 0.f, 0.f, 0.f, 0.f, 0.f, 0.f, 0.f};
#pragma unroll
    for (int d = -4; d <= 4; ++d) {
      if ((unsigned)(s + d) < 4096u) {  // wave-uniform branch
        f32x4 v0 = *(const f32x4*)(base + (long)d * EDIM);
        f32x4 v1 = *(const f32x4*)(base + (long)d * EDIM + 4);
        float g = G[d < 0 ? -d : d];
#pragma unroll
        for (int q = 0; q < 4; ++q) { a[q] += g * v0[q]; a[4 + q] += g * v1[q]; }
      }
    }
    u16x8 o;
#pragma unroll
    for (int q = 0; q < 8; ++q) o[q] = f2b(a[q]);
    *(u16x8*)(Uo + (u64)r * EDIM + c) = o;
  }
}

// ---------------------------------------------------------------------------
// gemm_out: out[16384,512] = U @ M^T, bf16 inputs, fp32 out.
// 128x128 tile, BK=64, 8 steps, A+B via global_load_lds w16 (pre-swizzled
// source octet (t&7)^((t>>3)&7), XOR-swizzled ds_read), double-buffered,
// ONE barrier/step: [vmcnt(0); s_barrier; issue kt+1 -> buf^1; compute buf].
// Grid 512 = 2 blocks/CU exactly (64KB LDS) -> all blocks resident.
// ---------------------------------------------------------------------------
__global__ __launch_bounds__(256) void gemm_out(const u16* __restrict__ U,
                                                const u16* __restrict__ Mm,
                                                float* __restrict__ out) {
  __shared__ u16 lds[32768];  // A0@0 A1@8192 B0@16384 B1@24576 (u16 offsets)
  int t = threadIdx.x;
  int l = t & 63, lr = l & 15, lk = l >> 4;
  int wv = t >> 6, wr = wv >> 1, wc = wv & 1;
  int b = (int)blockIdx.x;
  int wg = (b & 7) * 64 + (b >> 3);  // 512 % 8 == 0: simple bijective XCD swizzle
  int m0 = (wg >> 2) * 128;
  int n0 = (wg & 3) * 128;

  // staging: thread covers rows (t>>3)+32i, source octet pre-swizzled
  int soct = (t & 7) ^ ((t >> 3) & 7);
  const u16* gA = U + (u64)(m0 + (t >> 3)) * EDIM + soct * 8;
  const u16* gB = Mm + (u64)(n0 + (t >> 3)) * EDIM + soct * 8;

  // fragment read bases + row-swizzle
  int ard[4], aswz[4], brd[4], bswz[4];
#pragma unroll
  for (int mi = 0; mi < 4; ++mi) {
    int rA = wr * 64 + mi * 16 + lr;
    ard[mi] = rA * 64; aswz[mi] = (rA & 7) << 3;
  }
#pragma unroll
  for (int ni = 0; ni < 4; ++ni) {
    int rB = wc * 64 + ni * 16 + lr;
    brd[ni] = rB * 64; bswz[ni] = (rB & 7) << 3;
  }

  f32x4 acc[4][4] = {};

  // prologue: issue tile 0 into buf0
#pragma unroll
  for (int i = 0; i < 4; ++i) async_cp16(gA + (u64)i * 32 * EDIM, lds + t * 8 + i * 2048);
#pragma unroll
  for (int i = 0; i < 4; ++i) async_cp16(gB + (u64)i * 32 * EDIM, lds + 16384 + t * 8 + i * 2048);

#pragma unroll
  for (int kt = 0; kt < 8; ++kt) {
    asm volatile("s_waitcnt vmcnt(0)" ::: "memory");  // tile kt landed (issued 1 step ago)
    __builtin_amdgcn_sched_barrier(0);
    __builtin_amdgcn_s_barrier();  // all waves' tile-kt writes visible; all reads of buf^1 retired
    if (kt < 7) {                  // issue kt+1 into buf^1; in flight during compute
      int ko = (kt + 1) * 64;
      int ab = ((kt + 1) & 1) * 8192, bb = 16384 + ((kt + 1) & 1) * 8192;
#pragma unroll
      for (int i = 0; i < 4; ++i) async_cp16(gA + ko + (u64)i * 32 * EDIM, lds + ab + t * 8 + i * 2048);
#pragma unroll
      for (int i = 0; i < 4; ++i) async_cp16(gB + ko + (u64)i * 32 * EDIM, lds + bb + t * 8 + i * 2048);
    }
    __builtin_amdgcn_sched_barrier(0);
    int ab = (kt & 1) * 8192, bb = 16384 + (kt & 1) * 8192;
#pragma unroll
    for (int kk = 0; kk < 64; kk += 32) {
      bf16x8 af[4], bv[4];
#pragma unroll
      for (int mi = 0; mi < 4; ++mi)
        af[mi] = *(const bf16x8*)(lds + ab + ard[mi] + ((kk + lk * 8) ^ aswz[mi]));
#pragma unroll
      for (int ni = 0; ni < 4; ++ni)
        bv[ni] = *(const bf16x8*)(lds + bb + brd[ni] + ((kk + lk * 8) ^ bswz[ni]));
#pragma unroll
      for (int mi = 0; mi < 4; ++mi)
#pragma unroll
        for (int ni = 0; ni < 4; ++ni)
          acc[mi][ni] = __builtin_amdgcn_mfma_f32_16x16x32_bf16(af[mi], bv[ni],
                                                                acc[mi][ni], 0, 0, 0);
    }
  }

  // epilogue: fp32 stores
#pragma unroll
  for (int mi = 0; mi < 4; ++mi)
#pragma unroll
    for (int ni = 0; ni < 4; ++ni)
#pragma unroll
      for (int rr = 0; rr < 4; ++rr)
        out[(u64)(m0 + wr * 64 + mi * 16 + lk * 4 + rr) * EDIM +
            n0 + wc * 64 + ni * 16 + lr] = acc[mi][ni][rr];
}

extern "C" void kernel_launch(void* const* d_in, const int* in_sizes, int n_in,
                              void* d_out, int out_size, void* d_ws, size_t ws_size,
                              hipStream_t stream) {
  const float* in   = (const float*)d_in[0];  // [4,4096,512] f32
  const float* Win  = (const float*)d_in[1];  // [512,512] f32
  const float* Wout = (const float*)d_in[2];  // [512,512] f32
  float* outp = (float*)d_out;                // [4,4096,512] f32

  u16* Mm = (u16*)d_ws;                       // 512*512 bf16
  u16* Uo = (u16*)d_ws + (u64)EDIM * EDIM;    // 16384*512 bf16

  hipLaunchKernelGGL(prep,     dim3(64 + NCONVB), dim3(256), 0, stream, in, Win, Wout, Mm, Uo);
  hipLaunchKernelGGL(gemm_out, dim3(GOUT),        dim3(256), 0, stream, Uo, Mm, outp);
}